// Round 3
// baseline (1584.326 us; speedup 1.0000x reference)
//
#include <hip/hip_runtime.h>

#define BLK 256

// ---------------- helpers ----------------

__device__ __forceinline__ int edge_at(const void* idx, int is64, long long pos) {
  return is64 ? (int)((const long long*)idx)[pos] : ((const int*)idx)[pos];
}

// physical XCD id (0..7) — hwreg(HW_REG_XCC_ID=20, offset 0, size 4)
__device__ __forceinline__ int xcc_id() {
  return (int)(__builtin_amdgcn_s_getreg(6164) & 7);
}

// fp32 atomic add WITHOUT sc bits -> executes as RMW in the local XCD's TCC (L2),
// cached write-back, no memory-side transaction. Only correct because each
// target replica is keyed by physical XCC id.
__device__ __forceinline__ void atomic_add_xcd(float* p, float v) {
  asm volatile("global_atomic_add_f32 %0, %1, off" :: "v"(p), "v"(v) : "memory");
}

__device__ __forceinline__ void drain_vm() {
  asm volatile("s_waitcnt vmcnt(0)" ::: "memory");
}

// Detect int64 vs int32 storage: for int64 values < 2^31 the odd 32-bit words are 0.
__global__ void k_detect(const unsigned* __restrict__ w, int* __restrict__ flag) {
  __shared__ int any;
  if (threadIdx.x == 0) any = 0;
  __syncthreads();
  if (w[2 * threadIdx.x + 1] != 0u) atomicOr(&any, 1);
  __syncthreads();
  if (threadIdx.x == 0) *flag = (any == 0) ? 1 : 0;  // 1 => int64
}

__global__ void k_zero(float* __restrict__ p, int n) {
  int i = blockIdx.x * blockDim.x + threadIdx.x;
  if (i < n) p[i] = 0.0f;
}

// ---------------- per-XCD replica path ----------------

// degree histogram into per-XCD float replicas
__global__ void k_deg8(const void* __restrict__ ei, const int* __restrict__ flag,
                       int E, int N, float* __restrict__ degc) {
  int i = blockIdx.x * blockDim.x + threadIdx.x;
  if (i >= E) return;
  int is64 = *flag;
  int d = edge_at(ei, is64, (long long)E + i);
  float* base = degc + (size_t)xcc_id() * N;
  atomic_add_xcd(&base[d], 1.0f);
  drain_vm();
}

// reduce deg replicas -> dinv, gx4 = dinv * x (padded float4)
__global__ void k_prep8(const float* __restrict__ degc, int N,
                        const float* __restrict__ x,
                        float* __restrict__ dinv, float4* __restrict__ gx4) {
  int n = blockIdx.x * blockDim.x + threadIdx.x;
  if (n >= N) return;
  float deg = 1.0f;  // self-loop
#pragma unroll
  for (int c = 0; c < 8; ++c) deg += degc[(size_t)c * N + n];
  float di = rsqrtf(deg);
  dinv[n] = di;
  float4 g;
  g.x = di * x[3 * n + 0];
  g.y = di * x[3 * n + 1];
  g.z = di * x[3 * n + 2];
  g.w = 0.0f;
  gx4[n] = g;
}

// layer-1 scatter: aggx[xcc][3d+k] += gx[s][k]
__global__ void k_scat1_8(const void* __restrict__ ei, const int* __restrict__ flag,
                          int E, int N, const float4* __restrict__ gx4,
                          float* __restrict__ aggx) {
  int i = blockIdx.x * blockDim.x + threadIdx.x;
  if (i >= E) return;
  int is64 = *flag;
  int s = edge_at(ei, is64, i);
  int d = edge_at(ei, is64, (long long)E + i);
  float4 g = gx4[s];
  float* base = aggx + (size_t)xcc_id() * 3 * N + 3 * d;
  atomic_add_xcd(base + 0, g.x);
  atomic_add_xcd(base + 1, g.y);
  atomic_add_xcd(base + 2, g.z);
  drain_vm();
}

// reduce layer-1 replicas + self-loop, fused W1+b1+relu+W2 -> g2
__global__ void k_mid8(const float* __restrict__ aggx, int N,
                       const float4* __restrict__ gx4, const float* __restrict__ dinv,
                       const float* __restrict__ W1, const float* __restrict__ b1,
                       const float* __restrict__ W2, float* __restrict__ g2) {
  int n = blockIdx.x * blockDim.x + threadIdx.x;
  if (n >= N) return;
  float4 g = gx4[n];
  float a0 = g.x, a1 = g.y, a2 = g.z;  // self-loop term
#pragma unroll
  for (int c = 0; c < 8; ++c) {
    const float* pp = aggx + (size_t)c * 3 * N + 3 * n;
    a0 += pp[0]; a1 += pp[1]; a2 += pp[2];
  }
  float di = dinv[n];
  a0 *= di; a1 *= di; a2 *= di;
  float h2 = 0.0f;
#pragma unroll
  for (int k = 0; k < 16; ++k) {
    float o = fmaf(a0, W1[k], fmaf(a1, W1[16 + k], fmaf(a2, W1[32 + k], b1[k])));
    o = fmaxf(o, 0.0f);
    h2 = fmaf(o, W2[k], h2);
  }
  g2[n] = di * h2;
}

// layer-2 scatter: agg2[xcc][d] += g2[s]
__global__ void k_scat2_8(const void* __restrict__ ei, const int* __restrict__ flag,
                          int E, int N, const float* __restrict__ g2,
                          float* __restrict__ agg2) {
  int i = blockIdx.x * blockDim.x + threadIdx.x;
  if (i >= E) return;
  int is64 = *flag;
  int s = edge_at(ei, is64, i);
  int d = edge_at(ei, is64, (long long)E + i);
  float* base = agg2 + (size_t)xcc_id() * N;
  atomic_add_xcd(&base[d], g2[s]);
  drain_vm();
}

// reduce layer-2 replicas + self-loop + bias -> out
__global__ void k_final8(const float* __restrict__ agg2, int N,
                         const float* __restrict__ g2, const float* __restrict__ dinv,
                         const float* __restrict__ b2, float* __restrict__ out) {
  int n = blockIdx.x * blockDim.x + threadIdx.x;
  if (n >= N) return;
  float s = g2[n];  // self-loop
#pragma unroll
  for (int c = 0; c < 8; ++c) s += agg2[(size_t)c * N + n];
  out[n] = dinv[n] * s + b2[0];
}

// ---------------- fallback (round-1 atomic) path ----------------

__global__ void k_deg(const void* __restrict__ idx, const int* __restrict__ flag,
                      int E, int* __restrict__ deg) {
  int i = blockIdx.x * blockDim.x + threadIdx.x;
  if (i >= E) return;
  int is64 = *flag;
  atomicAdd(&deg[edge_at(idx, is64, (long long)E + i)], 1);
}

__global__ void k_prep(const float* __restrict__ x, const int* __restrict__ deg,
                       float* __restrict__ dinv, float* __restrict__ gx, int N) {
  int n = blockIdx.x * blockDim.x + threadIdx.x;
  if (n >= N) return;
  float di = rsqrtf((float)(deg[n] + 1));
  dinv[n] = di;
  gx[3 * n + 0] = di * x[3 * n + 0];
  gx[3 * n + 1] = di * x[3 * n + 1];
  gx[3 * n + 2] = di * x[3 * n + 2];
}

__global__ void k_scat1(const void* __restrict__ idx, const int* __restrict__ flag,
                        int E, const float* __restrict__ gx, float* __restrict__ aggx) {
  int i = blockIdx.x * blockDim.x + threadIdx.x;
  if (i >= E) return;
  int is64 = *flag;
  int s = edge_at(idx, is64, i);
  int d = edge_at(idx, is64, (long long)E + i);
  unsafeAtomicAdd(&aggx[3 * d + 0], gx[3 * s + 0]);
  unsafeAtomicAdd(&aggx[3 * d + 1], gx[3 * s + 1]);
  unsafeAtomicAdd(&aggx[3 * d + 2], gx[3 * s + 2]);
}

__global__ void k_mid(const float* __restrict__ aggx, const float* __restrict__ gx,
                      const float* __restrict__ dinv,
                      const float* __restrict__ W1, const float* __restrict__ b1,
                      const float* __restrict__ W2, float* __restrict__ g2, int N) {
  int n = blockIdx.x * blockDim.x + threadIdx.x;
  if (n >= N) return;
  float di = dinv[n];
  float a0 = (aggx[3 * n + 0] + gx[3 * n + 0]) * di;
  float a1 = (aggx[3 * n + 1] + gx[3 * n + 1]) * di;
  float a2 = (aggx[3 * n + 2] + gx[3 * n + 2]) * di;
  float h2 = 0.0f;
#pragma unroll
  for (int k = 0; k < 16; ++k) {
    float o = fmaf(a0, W1[k], fmaf(a1, W1[16 + k], fmaf(a2, W1[32 + k], b1[k])));
    o = fmaxf(o, 0.0f);
    h2 = fmaf(o, W2[k], h2);
  }
  g2[n] = di * h2;
}

__global__ void k_scat2(const void* __restrict__ idx, const int* __restrict__ flag,
                        int E, const float* __restrict__ g2, float* __restrict__ agg2) {
  int i = blockIdx.x * blockDim.x + threadIdx.x;
  if (i >= E) return;
  int is64 = *flag;
  int s = edge_at(idx, is64, i);
  int d = edge_at(idx, is64, (long long)E + i);
  unsafeAtomicAdd(&agg2[d], g2[s]);
}

__global__ void k_final(const float* __restrict__ agg2, const float* __restrict__ g2,
                        const float* __restrict__ dinv, const float* __restrict__ b2,
                        float* __restrict__ out, int N) {
  int n = blockIdx.x * blockDim.x + threadIdx.x;
  if (n >= N) return;
  out[n] = dinv[n] * (agg2[n] + g2[n]) + b2[0];
}

// ---------------- launch ----------------

extern "C" void kernel_launch(void* const* d_in, const int* in_sizes, int n_in,
                              void* d_out, int out_size, void* d_ws, size_t ws_size,
                              hipStream_t stream) {
  const float* x  = (const float*)d_in[0];
  const void*  ei = d_in[1];
  const float* W1 = (const float*)d_in[2];
  const float* b1 = (const float*)d_in[3];
  const float* W2 = (const float*)d_in[4];
  const float* b2 = (const float*)d_in[5];
  float* out = (float*)d_out;

  const int N = in_sizes[0] / 3;   // 200000
  const int E = in_sizes[1] / 2;   // 6400000

  char* ws = (char*)d_ws;
  int* flag = (int*)ws;

  int gN = (N + BLK - 1) / BLK;
  int gE = (E + BLK - 1) / BLK;

  // replica-path layout (floats): degc 8N | aggx 24N | agg2 8N | dinv N | gx4 4N | g2 N
  size_t need = 256 + (size_t)46 * N * 4;

  if (ws_size >= need) {
    float* degc = (float*)(ws + 256);
    float* aggx = degc + (size_t)8 * N;
    float* agg2 = aggx + (size_t)24 * N;
    float* dinv = agg2 + (size_t)8 * N;
    float* gx4  = dinv + N;           // float4[N]
    float* g2   = gx4 + (size_t)4 * N;

    int gZ = (40 * N + BLK - 1) / BLK;  // degc+aggx+agg2 contiguous

    k_detect<<<1, 256, 0, stream>>>((const unsigned*)ei, flag);
    k_zero<<<gZ, BLK, 0, stream>>>(degc, 40 * N);
    k_deg8<<<gE, BLK, 0, stream>>>(ei, flag, E, N, degc);
    k_prep8<<<gN, BLK, 0, stream>>>(degc, N, x, dinv, (float4*)gx4);
    k_scat1_8<<<gE, BLK, 0, stream>>>(ei, flag, E, N, (const float4*)gx4, aggx);
    k_mid8<<<gN, BLK, 0, stream>>>(aggx, N, (const float4*)gx4, dinv, W1, b1, W2, g2);
    k_scat2_8<<<gE, BLK, 0, stream>>>(ei, flag, E, N, g2, agg2);
    k_final8<<<gN, BLK, 0, stream>>>(agg2, N, g2, dinv, b2, out);
  } else {
    // round-1 fallback
    int*   deg  = (int*)(ws + 256);
    float* aggx = (float*)(ws + 256 + 4ll * N);
    float* agg2 = (float*)(ws + 256 + 4ll * N * 4);
    float* dinv = (float*)(ws + 256 + 4ll * N * 5);
    float* gx   = (float*)(ws + 256 + 4ll * N * 6);
    float* g2   = (float*)(ws + 256 + 4ll * N * 9);

    int gZ = (5 * N + BLK - 1) / BLK;

    k_detect<<<1, 256, 0, stream>>>((const unsigned*)ei, flag);
    k_zero<<<gZ, BLK, 0, stream>>>((float*)deg, 5 * N);
    k_deg<<<gE, BLK, 0, stream>>>(ei, flag, E, deg);
    k_prep<<<gN, BLK, 0, stream>>>(x, deg, dinv, gx, N);
    k_scat1<<<gE, BLK, 0, stream>>>(ei, flag, E, gx, aggx);
    k_mid<<<gN, BLK, 0, stream>>>(aggx, gx, dinv, W1, b1, W2, g2, N);
    k_scat2<<<gE, BLK, 0, stream>>>(ei, flag, E, g2, agg2);
    k_final<<<gN, BLK, 0, stream>>>(agg2, g2, dinv, b2, out, N);
  }
}

// Round 4
// 276.465 us; speedup vs baseline: 5.7307x; 5.7307x over previous
//
#include <hip/hip_runtime.h>

#define BLK 256
#define PSH 12
#define PART 4096          // nodes per dst-bucket
#define G1 1024            // blocks in hist/partition passes
#define MAXB 64            // max buckets supported by LDS counters

// ---------------- helpers ----------------

__device__ __forceinline__ int edge_at(const void* idx, int is64, long long pos) {
  return is64 ? (int)((const long long*)idx)[pos] : ((const int*)idx)[pos];
}

// Detect int64 vs int32 storage: for int64 values < 2^31 the odd 32-bit words are 0.
__global__ void k_detect(const unsigned* __restrict__ w, int* __restrict__ flag) {
  __shared__ int any;
  if (threadIdx.x == 0) any = 0;
  __syncthreads();
  if (w[2 * threadIdx.x + 1] != 0u) atomicOr(&any, 1);
  __syncthreads();
  if (threadIdx.x == 0) *flag = (any == 0) ? 1 : 0;  // 1 => int64
}

// ---------------- bucketed (counting-sort) path ----------------

// per-block histogram of dst buckets; hist layout [bucket][block]
__global__ __launch_bounds__(BLK) void k_hist(const void* __restrict__ ei,
                                              const int* __restrict__ flag,
                                              int E, int chunk, int NB,
                                              int* __restrict__ hist) {
  __shared__ int cnt[MAXB];
  for (int j = threadIdx.x; j < NB; j += BLK) cnt[j] = 0;
  __syncthreads();
  int is64 = *flag;
  int beg = blockIdx.x * chunk, end = min(E, beg + chunk);
  for (int i = beg + threadIdx.x; i < end; i += BLK) {
    int d = edge_at(ei, is64, (long long)E + i);
    atomicAdd(&cnt[d >> PSH], 1);
  }
  __syncthreads();
  for (int j = threadIdx.x; j < NB; j += BLK) hist[(size_t)j * G1 + blockIdx.x] = cnt[j];
}

// deterministic scan: per-(bucket,block) relative offsets + bucket starts
__global__ void k_scan(const int* __restrict__ hist, int NB,
                       int* __restrict__ offs, int* __restrict__ ebstart) {
  __shared__ int tot[MAXB];
  int b = threadIdx.x;
  if (b < NB) {
    int run = 0;
    const int* h = hist + (size_t)b * G1;
    int* o = offs + (size_t)b * G1;
    for (int i = 0; i < G1; ++i) { o[i] = run; run += h[i]; }
    tot[b] = run;
  }
  __syncthreads();
  if (threadIdx.x == 0) {
    int run = 0;
    for (int j = 0; j < NB; ++j) { ebstart[j] = run; run += tot[j]; }
    ebstart[NB] = run;
  }
}

// partition: write packed (src<<12 | dst_local) into bucket-ordered array
__global__ __launch_bounds__(BLK) void k_part(const void* __restrict__ ei,
                                              const int* __restrict__ flag,
                                              int E, int chunk, int NB,
                                              const int* __restrict__ offs,
                                              const int* __restrict__ ebstart,
                                              int* __restrict__ packed) {
  __shared__ int cnt[MAXB];
  int t = threadIdx.x;
  if (t < NB) cnt[t] = ebstart[t] + offs[(size_t)t * G1 + blockIdx.x];
  __syncthreads();
  int is64 = *flag;
  int beg = blockIdx.x * chunk, end = min(E, beg + chunk);
  for (int i = beg + t; i < end; i += BLK) {
    int s = edge_at(ei, is64, i);
    int d = edge_at(ei, is64, (long long)E + i);
    int pos = atomicAdd(&cnt[d >> PSH], 1);
    packed[pos] = (s << PSH) | (d & (PART - 1));
  }
}

// degree count per bucket slice -> int partials [kb2][N]
__global__ __launch_bounds__(BLK) void k_degb(const int* __restrict__ packed,
                                              const int* __restrict__ ebstart,
                                              int N, int kb, int* __restrict__ degp) {
  __shared__ int cnt[PART];
  for (int j = threadIdx.x; j < PART; j += BLK) cnt[j] = 0;
  __syncthreads();
  int b = blockIdx.x, k = blockIdx.y;
  int s0 = ebstart[b], len = ebstart[b + 1] - s0;
  int lo = s0 + (int)((long long)len * k / kb);
  int hi = s0 + (int)((long long)len * (k + 1) / kb);
  for (int i = lo + threadIdx.x; i < hi; i += BLK)
    atomicAdd(&cnt[packed[i] & (PART - 1)], 1);
  __syncthreads();
  int pstart = b << PSH;
  int psize = min(N - pstart, PART);
  int* out = degp + (size_t)k * N + pstart;
  for (int j = threadIdx.x; j < psize; j += BLK) out[j] = cnt[j];
}

// reduce degree partials -> dinv, gx4 = dinv * x
__global__ void k_prepb(const int* __restrict__ degp, int kb2, int N,
                        const float* __restrict__ x,
                        float* __restrict__ dinv, float4* __restrict__ gx4) {
  int n = blockIdx.x * blockDim.x + threadIdx.x;
  if (n >= N) return;
  float deg = 1.0f;  // self-loop
  for (int k = 0; k < kb2; ++k) deg += (float)degp[(size_t)k * N + n];
  float di = rsqrtf(deg);
  dinv[n] = di;
  float4 g;
  g.x = di * x[3 * n + 0];
  g.y = di * x[3 * n + 1];
  g.z = di * x[3 * n + 2];
  g.w = 0.0f;
  gx4[n] = g;
}

// layer-1 aggregation in LDS -> float partials [kb][3N]
__global__ __launch_bounds__(BLK) void k_s1b(const int* __restrict__ packed,
                                             const int* __restrict__ ebstart,
                                             int N, int kb,
                                             const float4* __restrict__ gx4,
                                             float* __restrict__ p1) {
  __shared__ float acc[3 * PART];  // 48 KB
  for (int j = threadIdx.x; j < 3 * PART; j += BLK) acc[j] = 0.0f;
  __syncthreads();
  int b = blockIdx.x, k = blockIdx.y;
  int s0 = ebstart[b], len = ebstart[b + 1] - s0;
  int lo = s0 + (int)((long long)len * k / kb);
  int hi = s0 + (int)((long long)len * (k + 1) / kb);
  for (int i = lo + threadIdx.x; i < hi; i += BLK) {
    int e = packed[i];
    int dl = e & (PART - 1);
    float4 g = gx4[e >> PSH];
    unsafeAtomicAdd(&acc[3 * dl + 0], g.x);
    unsafeAtomicAdd(&acc[3 * dl + 1], g.y);
    unsafeAtomicAdd(&acc[3 * dl + 2], g.z);
  }
  __syncthreads();
  int pstart = b << PSH;
  int psize = min(N - pstart, PART);
  float* out = p1 + (size_t)k * 3 * N + 3 * pstart;
  for (int j = threadIdx.x; j < 3 * psize; j += BLK) out[j] = acc[j];
}

// reduce layer-1 partials + self-loop, fused W1+b1+relu+W2 -> g2
__global__ void k_midb(const float* __restrict__ p1, int kb, int N,
                       const float4* __restrict__ gx4, const float* __restrict__ dinv,
                       const float* __restrict__ W1, const float* __restrict__ b1,
                       const float* __restrict__ W2, float* __restrict__ g2) {
  int n = blockIdx.x * blockDim.x + threadIdx.x;
  if (n >= N) return;
  float4 g = gx4[n];
  float a0 = g.x, a1 = g.y, a2 = g.z;  // self-loop
  for (int k = 0; k < kb; ++k) {
    const float* pp = p1 + (size_t)k * 3 * N + 3 * n;
    a0 += pp[0]; a1 += pp[1]; a2 += pp[2];
  }
  float di = dinv[n];
  a0 *= di; a1 *= di; a2 *= di;
  float h2 = 0.0f;
#pragma unroll
  for (int k = 0; k < 16; ++k) {
    float o = fmaf(a0, W1[k], fmaf(a1, W1[16 + k], fmaf(a2, W1[32 + k], b1[k])));
    o = fmaxf(o, 0.0f);
    h2 = fmaf(o, W2[k], h2);
  }
  g2[n] = di * h2;
}

// layer-2 aggregation in LDS -> float partials [kb2][N]
__global__ __launch_bounds__(BLK) void k_s2b(const int* __restrict__ packed,
                                             const int* __restrict__ ebstart,
                                             int N, int kb,
                                             const float* __restrict__ g2,
                                             float* __restrict__ p2) {
  __shared__ float acc[PART];  // 16 KB
  for (int j = threadIdx.x; j < PART; j += BLK) acc[j] = 0.0f;
  __syncthreads();
  int b = blockIdx.x, k = blockIdx.y;
  int s0 = ebstart[b], len = ebstart[b + 1] - s0;
  int lo = s0 + (int)((long long)len * k / kb);
  int hi = s0 + (int)((long long)len * (k + 1) / kb);
  for (int i = lo + threadIdx.x; i < hi; i += BLK) {
    int e = packed[i];
    unsafeAtomicAdd(&acc[e & (PART - 1)], g2[e >> PSH]);
  }
  __syncthreads();
  int pstart = b << PSH;
  int psize = min(N - pstart, PART);
  float* out = p2 + (size_t)k * N + pstart;
  for (int j = threadIdx.x; j < psize; j += BLK) out[j] = acc[j];
}

// reduce layer-2 partials + self-loop + bias -> out
__global__ void k_finalb(const float* __restrict__ p2, int kb2, int N,
                         const float* __restrict__ g2, const float* __restrict__ dinv,
                         const float* __restrict__ b2, float* __restrict__ out) {
  int n = blockIdx.x * blockDim.x + threadIdx.x;
  if (n >= N) return;
  float s = g2[n];  // self-loop
  for (int k = 0; k < kb2; ++k) s += p2[(size_t)k * N + n];
  out[n] = dinv[n] * s + b2[0];
}

// ---------------- fallback (round-1 atomic) path ----------------

__global__ void k_zero(float* __restrict__ p, int n) {
  int i = blockIdx.x * blockDim.x + threadIdx.x;
  if (i < n) p[i] = 0.0f;
}

__global__ void k_deg(const void* __restrict__ idx, const int* __restrict__ flag,
                      int E, int* __restrict__ deg) {
  int i = blockIdx.x * blockDim.x + threadIdx.x;
  if (i >= E) return;
  int is64 = *flag;
  atomicAdd(&deg[edge_at(idx, is64, (long long)E + i)], 1);
}

__global__ void k_prep(const float* __restrict__ x, const int* __restrict__ deg,
                       float* __restrict__ dinv, float* __restrict__ gx, int N) {
  int n = blockIdx.x * blockDim.x + threadIdx.x;
  if (n >= N) return;
  float di = rsqrtf((float)(deg[n] + 1));
  dinv[n] = di;
  gx[3 * n + 0] = di * x[3 * n + 0];
  gx[3 * n + 1] = di * x[3 * n + 1];
  gx[3 * n + 2] = di * x[3 * n + 2];
}

__global__ void k_scat1(const void* __restrict__ idx, const int* __restrict__ flag,
                        int E, const float* __restrict__ gx, float* __restrict__ aggx) {
  int i = blockIdx.x * blockDim.x + threadIdx.x;
  if (i >= E) return;
  int is64 = *flag;
  int s = edge_at(idx, is64, i);
  int d = edge_at(idx, is64, (long long)E + i);
  unsafeAtomicAdd(&aggx[3 * d + 0], gx[3 * s + 0]);
  unsafeAtomicAdd(&aggx[3 * d + 1], gx[3 * s + 1]);
  unsafeAtomicAdd(&aggx[3 * d + 2], gx[3 * s + 2]);
}

__global__ void k_mid(const float* __restrict__ aggx, const float* __restrict__ gx,
                      const float* __restrict__ dinv,
                      const float* __restrict__ W1, const float* __restrict__ b1,
                      const float* __restrict__ W2, float* __restrict__ g2, int N) {
  int n = blockIdx.x * blockDim.x + threadIdx.x;
  if (n >= N) return;
  float di = dinv[n];
  float a0 = (aggx[3 * n + 0] + gx[3 * n + 0]) * di;
  float a1 = (aggx[3 * n + 1] + gx[3 * n + 1]) * di;
  float a2 = (aggx[3 * n + 2] + gx[3 * n + 2]) * di;
  float h2 = 0.0f;
#pragma unroll
  for (int k = 0; k < 16; ++k) {
    float o = fmaf(a0, W1[k], fmaf(a1, W1[16 + k], fmaf(a2, W1[32 + k], b1[k])));
    o = fmaxf(o, 0.0f);
    h2 = fmaf(o, W2[k], h2);
  }
  g2[n] = di * h2;
}

__global__ void k_scat2(const void* __restrict__ idx, const int* __restrict__ flag,
                        int E, const float* __restrict__ g2, float* __restrict__ agg2) {
  int i = blockIdx.x * blockDim.x + threadIdx.x;
  if (i >= E) return;
  int is64 = *flag;
  int s = edge_at(idx, is64, i);
  int d = edge_at(idx, is64, (long long)E + i);
  unsafeAtomicAdd(&agg2[d], g2[s]);
}

__global__ void k_final(const float* __restrict__ agg2, const float* __restrict__ g2,
                        const float* __restrict__ dinv, const float* __restrict__ b2,
                        float* __restrict__ out, int N) {
  int n = blockIdx.x * blockDim.x + threadIdx.x;
  if (n >= N) return;
  out[n] = dinv[n] * (agg2[n] + g2[n]) + b2[0];
}

// ---------------- launch ----------------

extern "C" void kernel_launch(void* const* d_in, const int* in_sizes, int n_in,
                              void* d_out, int out_size, void* d_ws, size_t ws_size,
                              hipStream_t stream) {
  const float* x  = (const float*)d_in[0];
  const void*  ei = d_in[1];
  const float* W1 = (const float*)d_in[2];
  const float* b1 = (const float*)d_in[3];
  const float* W2 = (const float*)d_in[4];
  const float* b2 = (const float*)d_in[5];
  float* out = (float*)d_out;

  const int N = in_sizes[0] / 3;   // 200000
  const int E = in_sizes[1] / 2;   // 6400000
  const int NB = (N + PART - 1) >> PSH;

  char* ws = (char*)d_ws;
  int gN = (N + BLK - 1) / BLK;
  int gE = (E + BLK - 1) / BLK;

  // ws layout (256B-aligned cursor)
  size_t cur = 0;
  auto take = [&](size_t bytes) { size_t o = cur; cur += (bytes + 255) & ~(size_t)255; return (void*)(ws + o); };
  int*   flag    = (int*)take(256);
  int*   ebstart = (int*)take((size_t)(MAXB + 1) * 4);
  int*   hist    = (int*)take((size_t)MAXB * G1 * 4);
  int*   offs    = (int*)take((size_t)MAXB * G1 * 4);
  int*   packed  = (int*)take((size_t)E * 4);
  float* dinv    = (float*)take((size_t)N * 4);
  float* gx4     = (float*)take((size_t)N * 16);
  float* g2      = (float*)take((size_t)N * 4);
  size_t fixed = cur;

  // partial region: kb * 3N floats (reused as [3kb][N] ints / floats for deg & layer2)
  int kb = 8;
  while (kb >= 1 && fixed + (size_t)kb * 3 * N * 4 > ws_size) kb >>= 1;

  if (kb >= 1 && N <= (1 << 18) && NB <= MAXB) {
    float* partial = (float*)take((size_t)kb * 3 * N * 4);
    int kb2 = 3 * kb;
    int chunk = (E + G1 - 1) / G1;

    k_detect<<<1, 256, 0, stream>>>((const unsigned*)ei, flag);
    k_hist<<<G1, BLK, 0, stream>>>(ei, flag, E, chunk, NB, hist);
    k_scan<<<1, MAXB, 0, stream>>>(hist, NB, offs, ebstart);
    k_part<<<G1, BLK, 0, stream>>>(ei, flag, E, chunk, NB, offs, ebstart, packed);
    k_degb<<<dim3(NB, kb2), BLK, 0, stream>>>(packed, ebstart, N, kb2, (int*)partial);
    k_prepb<<<gN, BLK, 0, stream>>>((const int*)partial, kb2, N, x, dinv, (float4*)gx4);
    k_s1b<<<dim3(NB, kb), BLK, 0, stream>>>(packed, ebstart, N, kb, (const float4*)gx4, partial);
    k_midb<<<gN, BLK, 0, stream>>>(partial, kb, N, (const float4*)gx4, dinv, W1, b1, W2, g2);
    k_s2b<<<dim3(NB, kb2), BLK, 0, stream>>>(packed, ebstart, N, kb2, g2, partial);
    k_finalb<<<gN, BLK, 0, stream>>>(partial, kb2, N, g2, dinv, b2, out);
  } else {
    // round-1 fallback
    int*   deg  = (int*)(ws + 256);
    float* aggx = (float*)(ws + 256 + 4ll * N);
    float* agg2 = (float*)(ws + 256 + 4ll * N * 4);
    float* dinvf= (float*)(ws + 256 + 4ll * N * 5);
    float* gx   = (float*)(ws + 256 + 4ll * N * 6);
    float* g2f  = (float*)(ws + 256 + 4ll * N * 9);

    int gZ = (5 * N + BLK - 1) / BLK;

    k_detect<<<1, 256, 0, stream>>>((const unsigned*)ei, flag);
    k_zero<<<gZ, BLK, 0, stream>>>((float*)deg, 5 * N);
    k_deg<<<gE, BLK, 0, stream>>>(ei, flag, E, deg);
    k_prep<<<gN, BLK, 0, stream>>>(x, deg, dinvf, gx, N);
    k_scat1<<<gE, BLK, 0, stream>>>(ei, flag, E, gx, aggx);
    k_mid<<<gN, BLK, 0, stream>>>(aggx, gx, dinvf, W1, b1, W2, g2f, N);
    k_scat2<<<gE, BLK, 0, stream>>>(ei, flag, E, g2f, agg2);
    k_final<<<gN, BLK, 0, stream>>>(agg2, g2f, dinvf, b2, out, N);
  }
}